// Round 14
// baseline (241.049 us; speedup 1.0000x reference)
//
#include <hip/hip_runtime.h>

// Shapes: B=64, N=197, C=768, H=12, hd=64
// qkv/proj GEMM: 128x256 tile (acc[4][8]), BK=32, FULL double-buffer (48KB),
//   2-phase schedule: stage tile t+1 -> counted s_waitcnt vmcnt(6) -> raw
//   s_barrier -> ds_read+32 MFMA -> raw barrier. Loads overlap compute
//   (catalog T3-minimum, +10% same-probe). K order unchanged -> bit-identical.
//   32-col swizzle: LDS[row][slot] = chunk slot^((row>>1)&3) -- verified
//   2-way-max banks on b128 reads. XCD-chunked bijective block swizzle.
// Attention: r13 (Kl swizzled K-in-LDS + VS=212 + paired q-tiles). Untouched.
// prepare = fused convert + bias gather.

#define NB   64
#define NN   197
#define NC   768
#define NH   12
#define HD   64
#define MM   (NB*NN)      // 12608
#define MR   12672        // 99*128
#define NP   208          // 13*16
#define VS   212          // Vt / P row stride (ushorts); 106 dwords == 10 mod 32
#define SZQ  ((size_t)NB * NH * NN * HD)
#define CVTQ ((MM + 2304 + 768) * 192)
#define BIASN (NH * 13 * 13 * 256)

typedef unsigned short ushort_t;
typedef __attribute__((ext_vector_type(8))) short short8;
typedef __attribute__((ext_vector_type(4))) float f32x4;
union U128 { uint4 u; short8 s; };

__device__ __forceinline__ unsigned bf16_rne(float f) {
    unsigned u = __float_as_uint(f);
    return (u + 0x7fffu + ((u >> 16) & 1u)) >> 16;
}

__device__ __forceinline__ void gld16(unsigned short* lds, const unsigned short* g) {
    __builtin_amdgcn_global_load_lds(
        (const __attribute__((address_space(1))) void*)g,
        (__attribute__((address_space(3))) void*)lds, 16, 0, 0);
}

#define RAWBAR() do { asm volatile("" ::: "memory"); \
                      __builtin_amdgcn_s_barrier();  \
                      asm volatile("" ::: "memory"); } while (0)

// ---------------------------------------------------------------------------
// prepare: x->xh, w_qkv->wh, w_proj->wp (bf16) AND biasP fragment gather.
// ---------------------------------------------------------------------------
__global__ __launch_bounds__(256) void prepare(
    const float* __restrict__ x, const float* __restrict__ w_qkv,
    const float* __restrict__ w_proj, const float* __restrict__ table,
    const int* __restrict__ rel_index,
    ushort_t* __restrict__ xh, ushort_t* __restrict__ wh,
    ushort_t* __restrict__ wp, float* __restrict__ biasP)
{
    int idx = blockIdx.x * 256 + threadIdx.x;
    if (idx < CVTQ) {
        int r = idx / 192;
        int c = (idx - r * 192) * 4;
        const float* src;
        ushort_t* dsth;
        if (r < MM) {
            src = x + (size_t)r * NC; dsth = xh + (size_t)r * NC + c;
        } else if (r < MM + 2304) {
            int rr = r - MM;
            src = w_qkv + (size_t)rr * NC; dsth = wh + (size_t)rr * NC + c;
        } else {
            int rr = r - MM - 2304;
            src = w_proj + (size_t)rr * NC; dsth = wp + (size_t)rr * NC + c;
        }
        float4 f = *(const float4*)(src + c);
        ushort4 hv = { (ushort_t)bf16_rne(f.x), (ushort_t)bf16_rne(f.y),
                       (ushort_t)bf16_rne(f.z), (ushort_t)bf16_rne(f.w) };
        *(ushort4*)dsth = hv;
    } else {
        int i = idx - CVTQ;
        if (i < BIASN) {
            int r = i & 3, l15 = (i >> 2) & 15, quad = (i >> 6) & 3;
            int t = i >> 8;
            int kt = t % 13; int t2 = t / 13;
            int qt = t2 % 13; int h = t2 / 13;
            int n = qt * 16 + quad * 4 + r;
            int m = kt * 16 + l15;
            float v = -1e30f;
            if (n < NN && m < NN) v = table[rel_index[n * NN + m] * NH + h];
            biasP[i] = v;
        }
    }
}

// ---------------------------------------------------------------------------
// 2-phase double-buffered bf16 MFMA mainloop, 128(M) x 256(N), BK=32.
// LDS: A 2x[128][32], B 2x[256][32]. Stage next tile, wait vmcnt(6) (tile t's
// 6 loads landed; t+1's 6 in flight), raw barrier, 12 ds_read_b128 + 32 MFMA,
// raw barrier. Swizzle: LDS[row][slot s] holds global chunk s^((row>>1)&3);
// stage source pre-swizzled (DMA stays linear); read slot = quad^((l15>>1)&3)
// -> each quarter-wave hits every 4-bank span exactly twice (free, m136).
// ---------------------------------------------------------------------------
__device__ __forceinline__ void gemm_mainloop(
    const ushort_t* __restrict__ A2, int sA,
    const ushort_t* __restrict__ B2, int sB,
    int m0, int n0, int kiters, ushort_t* Abuf, ushort_t* Bbuf, f32x4 acc[4][8])
{
    const int tid = threadIdx.x;
    const int w = tid >> 6, lane = tid & 63;
    const int wm = w & 1, wn = w >> 1;
    const int quad = lane >> 4, l15 = lane & 15;
    const int lrow = lane >> 2;                       // 0..15
    const int gch = (lane & 3) ^ ((lane >> 3) & 3);   // pre-swizzled src chunk

    // per-lane global row bases (k advances 32 per step)
    const ushort_t* Ag0 = A2 + (size_t)(m0 + w * 32 + lrow) * sA + gch * 8;
    const ushort_t* Bg0 = B2 + (size_t)(n0 + w * 64 + lrow) * sB + gch * 8;

    // wave-uniform LDS staging bases (lane scatters linearly at 16B)
    ushort_t* Ad0 = Abuf + w * 1024;   // rows w*32 + [it*16..], 512 ushorts/it
    ushort_t* Bd0 = Bbuf + w * 2048;   // rows w*64 + [it*16..]

#define STAGE(curb, koff) do {                                   \
    gld16(Ad0 + (curb) * 4096,        Ag0 + (koff));             \
    gld16(Ad0 + (curb) * 4096 + 512,  Ag0 + (size_t)16 * sA + (koff)); \
    gld16(Bd0 + (curb) * 8192,        Bg0 + (koff));             \
    gld16(Bd0 + (curb) * 8192 + 512,  Bg0 + (size_t)16 * sB + (koff)); \
    gld16(Bd0 + (curb) * 8192 + 1024, Bg0 + (size_t)32 * sB + (koff)); \
    gld16(Bd0 + (curb) * 8192 + 1536, Bg0 + (size_t)48 * sB + (koff)); \
} while (0)

    const int rs = (quad ^ ((l15 >> 1) & 3)) << 3;    // read slot offset
    int aoff[4], boff[8];
    #pragma unroll
    for (int i = 0; i < 4; i++)
        aoff[i] = (wm * 64 + i * 16 + l15) * 32 + rs;
    #pragma unroll
    for (int j = 0; j < 8; j++)
        boff[j] = (wn * 128 + j * 16 + l15) * 32 + rs;

    STAGE(0, 0);                                      // prologue: tile 0

    for (int t = 0; t < kiters; ++t) {
        const int cur = t & 1;
        if (t + 1 < kiters) {
            STAGE(cur ^ 1, (size_t)(t + 1) * 32);     // next tile in flight
            asm volatile("s_waitcnt vmcnt(6)" ::: "memory");  // tile t landed
        } else {
            asm volatile("s_waitcnt vmcnt(0)" ::: "memory");
        }
        RAWBAR();                                     // tile t visible to all

        const ushort_t* Ac = Abuf + cur * 4096;
        const ushort_t* Bc = Bbuf + cur * 8192;
        U128 af[4], bf[8];
        #pragma unroll
        for (int i = 0; i < 4; i++) af[i].u = *(const uint4*)&Ac[aoff[i]];
        #pragma unroll
        for (int j = 0; j < 8; j++) bf[j].u = *(const uint4*)&Bc[boff[j]];
        #pragma unroll
        for (int i = 0; i < 4; i++)
            #pragma unroll
            for (int j = 0; j < 8; j++)
                acc[i][j] = __builtin_amdgcn_mfma_f32_16x16x32_bf16(
                    af[i].s, bf[j].s, acc[i][j], 0, 0, 0);

        RAWBAR();   // all waves done reading buf[cur] before it is restaged
    }
#undef STAGE
}

// XCD-bijective chunked remap: consecutive f within one XCD.
__device__ __forceinline__ int xcd_remap(int bid, int nwg) {
    int q8 = nwg >> 3, r8 = nwg & 7;
    int xcd = bid & 7, loc = bid >> 3;
    return (xcd < r8 ? xcd * (q8 + 1) : r8 * (q8 + 1) + (xcd - r8) * q8) + loc;
}

// GEMM1: xh[MR,768] * wh[2304,768]^T -> qbf (scaled), kbf, vbf. 891 blocks.
__global__ __launch_bounds__(256, 2) void gemm_qkv_mfma(
    const ushort_t* __restrict__ A2, const ushort_t* __restrict__ B2,
    ushort_t* __restrict__ qbf, ushort_t* __restrict__ kbf,
    ushort_t* __restrict__ vbf)
{
    __shared__ ushort_t Abuf[2 * 128 * 32];   // 16 KB
    __shared__ ushort_t Bbuf[2 * 256 * 32];   // 32 KB
    f32x4 acc[4][8];
    f32x4 z = {0.f, 0.f, 0.f, 0.f};
    #pragma unroll
    for (int i = 0; i < 4; i++)
        #pragma unroll
        for (int j = 0; j < 8; j++) acc[i][j] = z;

    int f = xcd_remap(blockIdx.x, 891);
    int mt_ = f / 9, nt_ = f - mt_ * 9;
    const int m0 = mt_ * 128, n0 = nt_ * 256;
    gemm_mainloop(A2, NC, B2, NC, m0, n0, 24, Abuf, Bbuf, acc);

    __syncthreads();                         // Abuf free for reuse as scratch

    const int tid = threadIdx.x;
    const int w = tid >> 6, lane = tid & 63;
    const int wm = w & 1, wn = w >> 1;
    const int quad = lane >> 4, l15 = lane & 15;

    ushort_t* Sw = Abuf + w * 1152;
    const int orow = lane >> 2;
    const int dch = (lane & 3) << 3;
    #pragma unroll
    for (int mt = 0; mt < 4; mt++) {
        int m = m0 + wm * 64 + mt * 16 + orow;
        int b_ = m / NN, n_ = m - b_ * NN;
        bool mv = (m < MM);
        #pragma unroll
        for (int g = 0; g < 2; g++) {
            int cg = n0 + wn * 128 + g * 64;
            int tq = cg / NC;
            int wi = cg - tq * NC;
            int hh = wi >> 6;
            ushort_t* dst = (tq == 0) ? qbf : (tq == 1) ? kbf : vbf;
            float scale = (tq == 0) ? 0.125f : 1.0f;
            #pragma unroll
            for (int nt = 0; nt < 4; nt++)
                #pragma unroll
                for (int r = 0; r < 4; r++)
                    Sw[(quad * 4 + r) * 72 + nt * 16 + l15] =
                        (ushort_t)bf16_rne(acc[mt][g * 4 + nt][r] * scale);
            if (mv) {
                size_t rb = ((size_t)(b_ * NH + hh) * NN + n_) * HD;
                uint4 v0 = *(const uint4*)&Sw[orow * 72 + dch];
                uint4 v1 = *(const uint4*)&Sw[orow * 72 + dch + 32];
                *(uint4*)&dst[rb + dch] = v0;
                *(uint4*)&dst[rb + dch + 32] = v1;
            }
        }
    }
}

// GEMM2: ab[MR,768] * wp[768,768]^T + bias -> out fp32. 297 blocks.
__global__ __launch_bounds__(256, 2) void gemm_proj_mfma(
    const ushort_t* __restrict__ A2, const ushort_t* __restrict__ B2,
    const float* __restrict__ bias, float* __restrict__ out)
{
    __shared__ ushort_t Abuf[2 * 128 * 32];
    __shared__ ushort_t Bbuf[2 * 256 * 32];
    f32x4 acc[4][8];
    f32x4 z = {0.f, 0.f, 0.f, 0.f};
    #pragma unroll
    for (int i = 0; i < 4; i++)
        #pragma unroll
        for (int j = 0; j < 8; j++) acc[i][j] = z;

    int f = xcd_remap(blockIdx.x, 297);
    int mt_ = f / 3, nt_ = f - mt_ * 3;
    const int m0 = mt_ * 128, n0 = nt_ * 256;
    gemm_mainloop(A2, NC, B2, NC, m0, n0, 24, Abuf, Bbuf, acc);

    const int tid = threadIdx.x;
    const int w = tid >> 6, lane = tid & 63;
    const int wm = w & 1, wn = w >> 1;
    const int quad = lane >> 4, l15 = lane & 15;
    #pragma unroll
    for (int nt = 0; nt < 8; nt++) {
        int col = n0 + wn * 128 + nt * 16 + l15;
        float bi = bias[col];
        #pragma unroll
        for (int mt = 0; mt < 4; mt++) {
            #pragma unroll
            for (int r = 0; r < 4; r++) {
                int m = m0 + wm * 64 + mt * 16 + quad * 4 + r;
                if (m < MM)
                    out[(size_t)m * NC + col] = acc[mt][nt][r] + bi;
            }
        }
    }
}

// ---------------------------------------------------------------------------
// MFMA attention. grid 768 x 256 threads (4 waves). One block per (b,h).
// Paired q-tiles per wave: A=w+rep*8, B=A+4. K/V fragments shared between
// A and B; SM_B overlaps PV_A. K in swizzled LDS; VS=212 strides.
// LDS 80896 B -> 2 blocks/CU. (r13, measured good -- untouched)
// ---------------------------------------------------------------------------
__global__ __launch_bounds__(256, 2) void attn_mfma(
    const ushort_t* __restrict__ qbf, const ushort_t* __restrict__ kbf,
    const ushort_t* __restrict__ vbf, const float* __restrict__ biasP,
    ushort_t* __restrict__ ab)
{
    __shared__ ushort_t Kl[NP * 64];         // 26624 B, GEMM-swizzle layout
    __shared__ ushort_t Vt[64 * VS];         // Vt[d][key], 27136 B
    __shared__ ushort_t Pl[4][16 * VS];      // per-wave P / V-stage / O-transpose

    const int bh = blockIdx.x;
    const int b = bh / NH, h = bh % NH;
    const int tid = threadIdx.x;
    const int w = tid >> 6, lane = tid & 63;
    const int quad = lane >> 4, l15 = lane & 15;
    const size_t base = (size_t)bh * (NN * HD);
    const ushort_t* kg = kbf + base;
    const ushort_t* vg = vbf + base;
    const ushort_t* qg = qbf + base;

    // ---- K stage: global -> reg -> swizzled LDS ----
    for (int idx = tid; idx < NP * 8; idx += 256) {
        int row = idx >> 3, ch = idx & 7;
        int srow = (row < NN) ? row : (NN - 1);
        uint4 val = *(const uint4*)(kg + (size_t)srow * HD + ch * 8);
        *(uint4*)&Kl[row * 64 + ((ch ^ (row & 7)) << 3)] = val;
    }

    // ---- stage V row-major coalesced, then LDS->LDS transpose into Vt ----
    ushort_t* Vstage = &Pl[0][0];            // 13312 ushorts <= 4*16*212
    for (int idx = tid; idx < NP * 8; idx += 256) {
        int row = idx >> 3, ch = idx & 7;
        uint4 val = {0u, 0u, 0u, 0u};
        if (row < NN) val = *(const uint4*)(vg + (size_t)row * HD + ch * 8);
        *(uint4*)&Vstage[row * HD + ch * 8] = val;
    }
    __syncthreads();                         // Kl + Vstage complete
    for (int task = tid; task < 64 * 26; task += 256) {
        int d = task & 63, kc = task >> 6;   // kc 0..25, keys < 208
        ushort_t tmp[8];
        #pragma unroll
        for (int j = 0; j < 8; j++)
            tmp[j] = Vstage[(kc * 8 + j) * HD + d];
        uint4 u;
        u.x = (unsigned)tmp[0] | ((unsigned)tmp[1] << 16);
        u.y = (unsigned)tmp[2] | ((unsigned)tmp[3] << 16);
        u.z = (unsigned)tmp[4] | ((unsigned)tmp[5] << 16);
        u.w = (unsigned)tmp[6] | ((unsigned)tmp[7] << 16);
        *(uint4*)&Vt[d * VS + kc * 8] = u;
    }
    __syncthreads();                         // Vt ready; Pl free

    const int ksl = (quad ^ (l15 & 7)) << 3; // K fragment slot (matches stage)
    ushort_t* P = Pl[w];

    #pragma unroll
    for (int rep = 0; rep < 2; rep++) {
        const int qtA = w + rep * 8;
        const int qtB = qtA + 4;
        const bool hasB = (qtB <= 12);       // wave-uniform

        // ---- tile A: Q frags + S init from bias ----
        const int q0A = qtA * 16;
        int qrA = q0A + l15; if (qrA > NN - 1) qrA = NN - 1;
        U128 qA0, qA1;
        qA0.u = *(const uint4*)(qg + (size_t)qrA * HD + quad * 8);
        qA1.u = *(const uint4*)(qg + (size_t)qrA * HD + 32 + quad * 8);
        f32x4 SA[13];
        const float* bpA = biasP + ((size_t)(h * 13 + qtA) * 13) * 256 + (quad << 6) + (l15 << 2);
        #pragma unroll
        for (int kt = 0; kt < 13; kt++) {
            float4 bv = *(const float4*)(bpA + kt * 256);
            SA[kt][0] = bv.x; SA[kt][1] = bv.y; SA[kt][2] = bv.z; SA[kt][3] = bv.w;
        }

        // ---- tile B (if any): Q frags + S init ----
        const int q0B = qtB * 16;
        U128 qB0, qB1;
        f32x4 SB[13];
        if (hasB) {
            int qrB = q0B + l15; if (qrB > NN - 1) qrB = NN - 1;
            qB0.u = *(const uint4*)(qg + (size_t)qrB * HD + quad * 8);
            qB1.u = *(const uint4*)(qg + (size_t)qrB * HD + 32 + quad * 8);
            const float* bpB = biasP + ((size_t)(h * 13 + qtB) * 13) * 256 + (quad << 6) + (l15 << 2);
            #pragma unroll
            for (int kt = 0; kt < 13; kt++) {
                float4 bv = *(const float4*)(bpB + kt * 256);
                SB[kt][0] = bv.x; SB[kt][1] = bv.y; SB[kt][2] = bv.z; SB[kt][3] = bv.w;
            }
        }

        // ---- QK^T: shared K fragments, 2 independent MFMA chains ----
        if (hasB) {
            #pragma unroll
            for (int kt = 0; kt < 13; kt++) {
                int ro = (kt * 16 + l15) * 64 + ksl;
                U128 k0, k1;
                k0.u = *(const uint4*)&Kl[ro];
                k1.u = *(const uint4*)&Kl[ro ^ 32];
                SA[kt] = __builtin_amdgcn_mfma_f32_16x16x32_bf16(qA0.s, k0.s, SA[kt], 0, 0, 0);
                SB[kt] = __builtin_amdgcn_mfma_f32_16x16x32_bf16(qB0.s, k0.s, SB[kt], 0, 0, 0);
                SA[kt] = __builtin_amdgcn_mfma_f32_16x16x32_bf16(qA1.s, k1.s, SA[kt], 0, 0, 0);
                SB[kt] = __builtin_amdgcn_mfma_f32_16x16x32_bf16(qB1.s, k1.s, SB[kt], 0, 0, 0);
            }
        } else {
            #pragma unroll
            for (int kt = 0; kt < 13; kt++) {
                int ro = (kt * 16 + l15) * 64 + ksl;
                U128 k0, k1;
                k0.u = *(const uint4*)&Kl[ro];
                k1.u = *(const uint4*)&Kl[ro ^ 32];
                SA[kt] = __builtin_amdgcn_mfma_f32_16x16x32_bf16(qA0.s, k0.s, SA[kt], 0, 0, 0);
                SA[kt] = __builtin_amdgcn_mfma_f32_16x16x32_bf16(qA1.s, k1.s, SA[kt], 0, 0, 0);
            }
        }

        // ---- SM_A + P_A store ----
        #pragma unroll
        for (int r = 0; r < 4; r++) {
            float mx = SA[0][r];
            #pragma unroll
            for (int kt = 1; kt < 13; kt++) mx = fmaxf(mx, SA[kt][r]);
            mx = fmaxf(mx, __shfl_xor(mx, 1));
            mx = fmaxf(mx, __shfl_xor(mx, 2));
            mx = fmaxf(mx, __shfl_xor(mx, 4));
            mx = fmaxf(mx, __shfl_xor(mx, 8));
            float sum = 0.f;
            #pragma unroll
            for (int kt = 0; kt < 13; kt++) {
                float e = __expf(SA[kt][r] - mx);
                SA[kt][r] = e;
                sum += e;
            }
            sum += __shfl_xor(sum, 1);
            sum += __shfl_xor(sum, 2);
            sum += __shfl_xor(sum, 4);
            sum += __shfl_xor(sum, 8);
            float inv = 1.0f / sum;
            int prow = quad * 4 + r;
            #pragma unroll
            for (int kt = 0; kt < 13; kt++)
                P[prow * VS + kt * 16 + l15] = (ushort_t)bf16_rne(SA[kt][r] * inv);
        }

        // ---- PV_A ----
        f32x4 OA[4];
        f32x4 z4 = {0.f, 0.f, 0.f, 0.f};
        #pragma unroll
        for (int dt = 0; dt < 4; dt++) OA[dt] = z4;
        #pragma unroll
        for (int ks = 0; ks < 7; ks++) {
            int pc = ks * 32 + quad * 8;
            bool vld = (pc < NP);
            int pcc = vld ? pc : 0;
            U128 pf;
            pf.u = *(const uint4*)&P[l15 * VS + pcc];
            if (!vld) { pf.u.x = 0u; pf.u.y = 0u; pf.u.z = 0u; pf.u.w = 0u; }
            #pragma unroll
            for (int dt = 0; dt < 4; dt++) {
                U128 vf;
                vf.u = *(const uint4*)&Vt[(dt * 16 + l15) * VS + pcc];
                OA[dt] = __builtin_amdgcn_mfma_f32_16x16x32_bf16(pf.s, vf.s, OA[dt], 0, 0, 0);
            }
        }

        // ---- SM_B (VALU; overlaps PV_A's MFMA stream) + P_B + PV_B ----
        f32x4 OB[4];
        if (hasB) {
            #pragma unroll
            for (int r = 0; r < 4; r++) {
                float mx = SB[0][r];
                #pragma unroll
                for (int kt = 1; kt < 13; kt++) mx = fmaxf(mx, SB[kt][r]);
                mx = fmaxf(mx, __shfl_xor(mx, 1));
                mx = fmaxf(mx, __shfl_xor(mx, 2));
                mx = fmaxf(mx, __shfl_xor(mx, 4));
                mx = fmaxf(mx, __shfl_xor(mx, 8));
                float sum = 0.f;
                #pragma unroll
                for (int kt = 0; kt < 13; kt++) {
                    float e = __expf(SB[kt][r] - mx);
                    SB[kt][r] = e;
                    sum += e;
                }
                sum += __shfl_xor(sum, 1);
                sum += __shfl_xor(sum, 2);
                sum += __shfl_xor(sum, 4);
                sum += __shfl_xor(sum, 8);
                float inv = 1.0f / sum;
                int prow = quad * 4 + r;
                #pragma unroll
                for (int kt = 0; kt < 13; kt++)
                    P[prow * VS + kt * 16 + l15] = (ushort_t)bf16_rne(SB[kt][r] * inv);
            }
            #pragma unroll
            for (int dt = 0; dt < 4; dt++) OB[dt] = z4;
            #pragma unroll
            for (int ks = 0; ks < 7; ks++) {
                int pc = ks * 32 + quad * 8;
                bool vld = (pc < NP);
                int pcc = vld ? pc : 0;
                U128 pf;
                pf.u = *(const uint4*)&P[l15 * VS + pcc];
                if (!vld) { pf.u.x = 0u; pf.u.y = 0u; pf.u.z = 0u; pf.u.w = 0u; }
                #pragma unroll
                for (int dt = 0; dt < 4; dt++) {
                    U128 vf;
                    vf.u = *(const uint4*)&Vt[(dt * 16 + l15) * VS + pcc];
                    OB[dt] = __builtin_amdgcn_mfma_f32_16x16x32_bf16(pf.s, vf.s, OB[dt], 0, 0, 0);
                }
            }
        }

        // ---- epilogue A ----
        {
            float* Osh = (float*)&Pl[w][0];  // stride 68 floats
            #pragma unroll
            for (int dt = 0; dt < 4; dt++)
                #pragma unroll
                for (int r = 0; r < 4; r++)
                    Osh[(quad * 4 + r) * 68 + dt * 16 + l15] = OA[dt][r];
            int orow = lane >> 2;
            int d0 = (lane & 3) << 4;
            int q = q0A + orow;
            if (q < NN) {
                unsigned hiw[8];
                #pragma unroll
                for (int k4 = 0; k4 < 4; k4++) {
                    float4 f = *(const float4*)&Osh[orow * 68 + d0 + k4 * 4];
                    unsigned h0 = bf16_rne(f.x), h1 = bf16_rne(f.y);
                    unsigned h2 = bf16_rne(f.z), h3 = bf16_rne(f.w);
                    hiw[k4 * 2]     = h0 | (h1 << 16);
                    hiw[k4 * 2 + 1] = h2 | (h3 << 16);
                }
                size_t baseo = ((size_t)b * NN + q) * NC + h * HD + d0;
                uint4 hA = {hiw[0], hiw[1], hiw[2], hiw[3]};
                uint4 hB = {hiw[4], hiw[5], hiw[6], hiw[7]};
                *(uint4*)&ab[baseo] = hA;
                *(uint4*)&ab[baseo + 8] = hB;
            }
        }
        // ---- epilogue B ----
        if (hasB) {
            float* Osh = (float*)&Pl[w][0];
            #pragma unroll
            for (int dt = 0; dt < 4; dt++)
                #pragma unroll
                for (int r = 0; r < 4; r++)
                    Osh[(quad * 4 + r) * 68 + dt * 16 + l15] = OB[dt][r];
            int orow = lane >> 2;
            int d0 = (lane & 3) << 4;
            int q = q0B + orow;
            if (q < NN) {
                unsigned hiw[8];
                #pragma unroll
                for (int k4 = 0; k4 < 4; k4++) {
                    float4 f = *(const float4*)&Osh[orow * 68 + d0 + k4 * 4];
                    unsigned h0 = bf16_rne(f.x), h1 = bf16_rne(f.y);
                    unsigned h2 = bf16_rne(f.z), h3 = bf16_rne(f.w);
                    hiw[k4 * 2]     = h0 | (h1 << 16);
                    hiw[k4 * 2 + 1] = h2 | (h3 << 16);
                }
                size_t baseo = ((size_t)b * NN + q) * NC + h * HD + d0;
                uint4 hA = {hiw[0], hiw[1], hiw[2], hiw[3]};
                uint4 hB = {hiw[4], hiw[5], hiw[6], hiw[7]};
                *(uint4*)&ab[baseo] = hA;
                *(uint4*)&ab[baseo + 8] = hB;
            }
        }
    }
}

// ---------------------------------------------------------------------------
extern "C" void kernel_launch(void* const* d_in, const int* in_sizes, int n_in,
                              void* d_out, int out_size, void* d_ws, size_t ws_size,
                              hipStream_t stream)
{
    const float* x        = (const float*)d_in[0];
    const float* table    = (const float*)d_in[1];
    const float* w_qkv    = (const float*)d_in[2];
    const float* w_proj   = (const float*)d_in[3];
    const float* b_proj   = (const float*)d_in[4];
    const int*   rel_idx  = (const int*)d_in[5];
    float* out = (float*)d_out;

    ushort_t* xh  = (ushort_t*)d_ws;                        // MR*768
    ushort_t* wh  = xh + (size_t)MR * NC;                   // 2304*768
    ushort_t* wp  = wh + (size_t)2304 * NC;                 // 768*768
    ushort_t* ab  = wp + (size_t)768 * NC;                  // MR*768
    ushort_t* qbf = ab + (size_t)MR * NC;                   // SZQ each
    ushort_t* kbf = qbf + SZQ;
    ushort_t* vbf = kbf + SZQ;
    float* biasP  = (float*)(vbf + SZQ);                    // BIASN f32

    const int ptot = CVTQ + BIASN;
    prepare<<<(ptot + 255) / 256, 256, 0, stream>>>(
        x, w_qkv, w_proj, table, rel_idx, xh, wh, wp, biasP);

    gemm_qkv_mfma<<<891, 256, 0, stream>>>(xh, wh, qbf, kbf, vbf);
    attn_mfma<<<768, 256, 0, stream>>>(qbf, kbf, vbf, biasP, ab);
    gemm_proj_mfma<<<297, 256, 0, stream>>>(ab, wp, b_proj, out);
}